// Round 9
// baseline (125.134 us; speedup 1.0000x reference)
//
#include <hip/hip_runtime.h>

// B=4096, F0=39, D=16, L=(128,128), H1=64
// Round-9: occupancy 4 waves/SIMD (4 batches/block, grid 1024) + symmetric layer-0 fold.
//  - Layer 0 uses W'[i,j] = W[i,j]+W[j,i] (j>i), diag kept, j<i zeroed: upper-tri
//    chunk list = 30 chunks (was 50). Total 110 chunks (was 130), exact math.
//  - mfma_f32_32x32x16_f16; wave = 2 M-tiles (4 batches) x col-quarter (disjoint B).
//  - B: f16 frag-order in d_ws (list-ordered chunks), global->VGPR, copy-free
//    distance-2 prefetch, no K-loop barriers. Layer-0 loop fully unrolled
//    (constexpr ig/jg tables -> compile-time xv register indices).
// Layouts (verified):
//  A: lane holds A[m=lane&31][k=(lane>>5)*8+t]
//  B: lane holds B[k=(lane>>5)*8+t][n=lane&31]
//  D: lane holds D[row=(r&3)+8*(r>>2)+4*(lane>>5)][col=lane&31]
// Repacked B layout (BYTES): ch*8192 + kh*4096 + cg*1024 + lane*16  (8 f16/lane)
//  L0 ch=0..29 (IG0/JG0 tables): i=ig*4+kh*2+half, j=jg*8+t; folded upper-tri.
//  L1 ch=30+jg*5+ig (jg<16,ig<5): j=jg*4+kh*2+half, i=ig*8+t, zero-pad i>=39.
// Total: 110 chunks * 8192 B = 901,120 B of d_ws.

typedef _Float16 h2    __attribute__((ext_vector_type(2)));
typedef _Float16 f16x8 __attribute__((ext_vector_type(8)));
typedef __attribute__((ext_vector_type(16))) float f32x16;

#define XBB 1160   // per-batch halfs in xsH: 16*72 + 8 skew
#define L0C 30
#define NCH 110

__device__ __constant__ int IG0[L0C] = {0,0,0,0,0, 1,1,1,1,1, 2,2,2,2, 3,3,3,3, 4,4,4, 5,5,5, 6,6, 7,7, 8, 9};
__device__ __constant__ int JG0[L0C] = {0,1,2,3,4, 0,1,2,3,4, 1,2,3,4, 1,2,3,4, 2,3,4, 2,3,4, 3,4, 3,4, 4, 4};
// host-side copies for compile-time unrolled indexing in main
#define IG0T(c) ((c)<5?0:(c)<10?1:(c)<14?2:(c)<18?3:(c)<21?4:(c)<24?5:(c)<26?6:(c)<28?7:(c)<29?8:9)
#define JG0T(c) ((c)<10?((c)%5):(c)<18?(((c)-10)%4+1):(c)<24?(((c)-18)%3+2):(c)<28?(((c)-24)%2+3):4)

// ---------------- weight repack: coalesced reads, f16 frag stores ----------------
__global__ __launch_bounds__(256)
void CIN_repack(const float* __restrict__ f0, const float* __restrict__ f1,
                uint4* __restrict__ ws)
{
    const int tid  = blockIdx.x * 256 + threadIdx.x;   // 56320 total
    const int n    = tid & 127;
    const int slot = tid >> 7;                          // 0..439
    const int half = slot & 1;
    const int kh   = (slot >> 1) & 1;
    const int ch   = slot >> 2;                         // 0..109
    float v[8];
    if (ch < L0C) {
        const int ig = IG0[ch], jg = JG0[ch];
        const int i = ig * 4 + kh * 2 + half;           // 0..39
#pragma unroll
        for (int t = 0; t < 8; ++t) {
            const int j = jg * 8 + t;                   // 0..39
            float val = 0.f;
            if (i < 39 && j < 39 && j >= i) {
                val = f0[(i * 39 + j) * 128 + n];
                if (j > i) val += f0[(j * 39 + i) * 128 + n];   // symmetric fold
            }
            v[t] = val;
        }
    } else {
        const int c1 = ch - L0C;
        const int jg = c1 / 5, ig = c1 - jg * 5;
        const int j = jg * 4 + kh * 2 + half;           // 0..63
#pragma unroll
        for (int t = 0; t < 8; ++t) {
            const int i = ig * 8 + t;                   // 0..39
            v[t] = (i < 39) ? f1[(i * 64 + j) * 128 + n] : 0.f;
        }
    }
    union { h2 h[4]; uint4 q; } pk;
#pragma unroll
    for (int t = 0; t < 4; ++t)
        pk.h[t] = h2{(_Float16)v[2 * t], (_Float16)v[2 * t + 1]};
    const int lane = half * 32 + (n & 31);
    const int cg   = n >> 5;
    ws[ch * 512 + kh * 256 + cg * 64 + lane] = pk.q;
}

// ---------------- main: grid 1024, 4 batches/block ----------------
__global__ __launch_bounds__(256, 4)
void CIN_main(const float* __restrict__ x,
              const char* __restrict__ wsB,
              const float* __restrict__ dw,
              const float* __restrict__ db,
              float* __restrict__ out)
{
    __shared__ __align__(16) _Float16 xsH[4 * XBB];    // [bb]: 16 rows of 72 (i<=39 used)
    __shared__ __align__(4)  _Float16 hsH[4][64][18];  // [bb][j][d]
    __shared__ float dws[192];
    __shared__ float red[4][4];

    const int tid  = threadIdx.x;
    const int w    = tid >> 6;     // col-quarter: n in [w*32, w*32+32)
    const int lane = tid & 63;
    const int half = lane >> 5;
    const int d    = lane & 15;
    const int bsel = (lane >> 4) & 1;
    const int col  = lane & 31;

    // B frag base; rebase +2048 so kh offsets {-2048,+2048} fit imm13
    const char* wbase = wsB + lane * 16 + w * 1024 + 2048;
    f16x8 Bb[2][2];                // [phase][kh]
    auto loadBg = [&](int ch, f16x8 (&B)[2]) {
        const char* p0 = wbase + (size_t)ch * 8192;
        B[0] = *(const f16x8*)(p0 - 2048);
        B[1] = *(const f16x8*)(p0 + 2048);
    };

    loadBg(0, Bb[0]);              // before x staging: latency hidden
    loadBg(1, Bb[1]);

    // ---- stage x for 4 batches as f16 (624 float4) ----
    const float4* xg4 = (const float4*)(x + (size_t)blockIdx.x * 4 * 624);
    for (int e4 = tid; e4 < 624; e4 += 256) {
        float4 v = xg4[e4];
        int bb = e4 / 156, r = e4 - bb * 156;
        int i = r >> 2, d0 = (r & 3) * 4;
        _Float16* bp = xsH + bb * XBB + i;
        bp[(d0 + 0) * 72] = (_Float16)v.x; bp[(d0 + 1) * 72] = (_Float16)v.y;
        bp[(d0 + 2) * 72] = (_Float16)v.z; bp[(d0 + 3) * 72] = (_Float16)v.w;
    }
    if (tid < 64) { int bb = tid >> 4, dd = tid & 15; xsH[bb * XBB + dd * 72 + 39] = (_Float16)0.f; }
    if (tid < 192) dws[tid] = dw[tid];
    __syncthreads();

    // ---- xv: per M-tile p, lane's batch row x[2p+bsel, :, d], packed f16 ----
    h2 xv[2][20];
#pragma unroll
    for (int p = 0; p < 2; ++p) {
        const uint4* src = (const uint4*)(xsH + (p * 2 + bsel) * XBB + d * 72);
#pragma unroll
        for (int q5 = 0; q5 < 5; ++q5) {
            union { uint4 q; h2 h[4]; } u;
            u.q = src[q5];
#pragma unroll
            for (int t = 0; t < 4; ++t) xv[p][q5 * 4 + t] = u.h[t];
        }
    }

    f32x16 acc[2];
#pragma unroll
    for (int p = 0; p < 2; ++p)
#pragma unroll
        for (int r = 0; r < 16; ++r) acc[p][r] = 0.f;

    h2 xiv2[2][2];

    // ---------------- layer 0: 30 folded chunks, fully unrolled ----------------
#pragma unroll
    for (int c = 0; c < L0C; ++c) {
        const int ig = IG0T(c);
        const int jg = JG0T(c);
        if (c == 0 || ig != IG0T(c - 1 < 0 ? 0 : c - 1)) {
#pragma unroll
            for (int p = 0; p < 2; ++p)
#pragma unroll
                for (int kh = 0; kh < 2; ++kh) {
                    _Float16 s = xsH[(p * 2 + bsel) * XBB + d * 72 + ig * 4 + kh * 2 + half];
                    xiv2[p][kh] = h2{s, s};
                }
        }
#pragma unroll
        for (int p = 0; p < 2; ++p) {
            union { h2 h[4]; f16x8 v; } a0, a1;
#pragma unroll
            for (int q = 0; q < 4; ++q) {
                a0.h[q] = xiv2[p][0] * xv[p][jg * 4 + q];   // v_pk_mul_f16
                a1.h[q] = xiv2[p][1] * xv[p][jg * 4 + q];
            }
            acc[p] = __builtin_amdgcn_mfma_f32_32x32x16_f16(a0.v, Bb[c & 1][0], acc[p], 0, 0, 0);
            acc[p] = __builtin_amdgcn_mfma_f32_32x32x16_f16(a1.v, Bb[c & 1][1], acc[p], 0, 0, 0);
        }
        loadBg(c + 2, Bb[c & 1]);   // max c+2 = 31 < 110, in bounds; fills L1 ch 30/31
    }

    // ---------------- layer-0 epilogue ----------------
    float cs[4] = {0.f, 0.f, 0.f, 0.f};
    if (w < 2) {
        // n = w*32+col < 64 -> h = relu(z0) into LDS (f16)
#pragma unroll
        for (int p = 0; p < 2; ++p)
#pragma unroll
            for (int r = 0; r < 16; r += 2) {
                const int row = (r & 3) + 8 * (r >> 2) + 4 * half;
                h2 pr = h2{(_Float16)fmaxf(acc[p][r],     0.f),
                           (_Float16)fmaxf(acc[p][r + 1], 0.f)};
                *(h2*)&hsH[p * 2 + (row >> 4)][w * 32 + col][row & 15] = pr;
            }
    } else {
        const float dwv = dws[(w - 2) * 32 + col];      // dw[n-64]
#pragma unroll
        for (int p = 0; p < 2; ++p)
#pragma unroll
            for (int r = 0; r < 16; ++r) {
                const int row = (r & 3) + 8 * (r >> 2) + 4 * half;
                cs[p * 2 + (row >> 4)] += fmaxf(acc[p][r], 0.f) * dwv;
            }
    }
#pragma unroll
    for (int p = 0; p < 2; ++p)
#pragma unroll
        for (int r = 0; r < 16; ++r) acc[p][r] = 0.f;
    __syncthreads();   // h visible to all waves

    // ---------------- layer 1: 8 outer x 10 unrolled chunks (30..109) ----------------
    // phase continuity: ch 30 -> parity 0 -> Bb[0] (prefetched at c=28) OK
#pragma unroll 1
    for (int o2 = 0; o2 < 8; ++o2) {
#pragma unroll
        for (int u = 0; u < 10; ++u) {
            const int ch = L0C + o2 * 10 + u;
            const int ig2 = u % 5;
            if (ig2 == 0) {
                const int jb = (o2 * 2 + u / 5) * 4;
#pragma unroll
                for (int p = 0; p < 2; ++p)
#pragma unroll
                    for (int kh = 0; kh < 2; ++kh) {
                        _Float16 s = hsH[p * 2 + bsel][jb + kh * 2 + half][d];
                        xiv2[p][kh] = h2{s, s};
                    }
            }
#pragma unroll
            for (int p = 0; p < 2; ++p) {
                union { h2 h[4]; f16x8 v; } a0, a1;
#pragma unroll
                for (int q = 0; q < 4; ++q) {
                    a0.h[q] = xiv2[p][0] * xv[p][ig2 * 4 + q];
                    a1.h[q] = xiv2[p][1] * xv[p][ig2 * 4 + q];
                }
                acc[p] = __builtin_amdgcn_mfma_f32_32x32x16_f16(a0.v, Bb[u & 1][0], acc[p], 0, 0, 0);
                acc[p] = __builtin_amdgcn_mfma_f32_32x32x16_f16(a1.v, Bb[u & 1][1], acc[p], 0, 0, 0);
            }
            int chn = ch + 2; if (chn > NCH - 1) chn = NCH - 1;
            loadBg(chn, Bb[u & 1]);
        }
    }

    // ---------------- layer-1 epilogue + reduction ----------------
    {
        const float dwv = dws[64 + w * 32 + col];
#pragma unroll
        for (int p = 0; p < 2; ++p)
#pragma unroll
            for (int r = 0; r < 16; ++r) {
                const int row = (r & 3) + 8 * (r >> 2) + 4 * half;
                cs[p * 2 + (row >> 4)] += fmaxf(acc[p][r], 0.f) * dwv;
            }
    }
#pragma unroll
    for (int rr = 0; rr < 4; ++rr)
#pragma unroll
        for (int off = 32; off > 0; off >>= 1)
            cs[rr] += __shfl_xor(cs[rr], off, 64);
    if (lane == 0) {
#pragma unroll
        for (int rr = 0; rr < 4; ++rr) red[w][rr] = cs[rr];
    }
    __syncthreads();
    if (tid < 4)
        out[blockIdx.x * 4 + tid] = red[0][tid] + red[1][tid] + red[2][tid] + red[3][tid] + db[0];
}

extern "C" void kernel_launch(void* const* d_in, const int* in_sizes, int n_in,
                              void* d_out, int out_size, void* d_ws, size_t ws_size,
                              hipStream_t stream)
{
    const float* x  = (const float*)d_in[0];
    const float* f0 = (const float*)d_in[1];
    const float* f1 = (const float*)d_in[2];
    const float* dw = (const float*)d_in[3];
    const float* db = (const float*)d_in[4];
    float* out = (float*)d_out;

    CIN_repack<<<dim3(220), dim3(256), 0, stream>>>(f0, f1, (uint4*)d_ws);
    CIN_main<<<dim3(1024), dim3(256), 0, stream>>>(x, (const char*)d_ws, dw, db, out);
}

// Round 10
// 124.880 us; speedup vs baseline: 1.0020x; 1.0020x over previous
//
#include <hip/hip_runtime.h>

// B=4096, F0=39, D=16, L=(128,128), H1=64
// Round-10: r9 (4 blocks/CU, symmetric-fold 110 chunks) with LDS-native A-operand path.
//  - r9's VGPR=64 proved the compiler demoted the xv register array to per-chunk
//    scalar LDS re-reads (live set ~110 regs vs 64 allocated) -> LDS pipe serialized
//    with MFMA + L1 B-stream (1353 cyc/chunk wall vs 512 MFMA).
//  - Fix: per chunk load the 8-half j/i-window as ONE aligned ds_read_b128 (f16x8),
//    16 v_pk_mul_f16 -> A-frags. No demotable array; unrolled regions can CSE the
//    5 distinct windows back into regs.
//  - mfma_f32_32x32x16_f16; wave = 2 M-tiles (4 batches) x col-quarter (disjoint B).
//  - B: f16 frag-order in d_ws, global->VGPR, copy-free distance-2 prefetch, no K barriers.
// Layouts (verified):
//  A: lane holds A[m=lane&31][k=(lane>>5)*8+t]
//  B: lane holds B[k=(lane>>5)*8+t][n=lane&31]
//  D: lane holds D[row=(r&3)+8*(r>>2)+4*(lane>>5)][col=lane&31]
// Repacked B layout (BYTES): ch*8192 + kh*4096 + cg*1024 + lane*16  (8 f16/lane)
//  L0 ch=0..29 (IG0/JG0 tables): i=ig*4+kh*2+half, j=jg*8+t; folded upper-tri
//    (W'[i,j]=W[i,j]+W[j,i] for j>i, diag kept, j<i zeroed).
//  L1 ch=30+jg*5+ig (jg<16,ig<5): j=jg*4+kh*2+half, i=ig*8+t, zero-pad i>=39.
// Total: 110 chunks * 8192 B = 901,120 B of d_ws.

typedef _Float16 h2    __attribute__((ext_vector_type(2)));
typedef _Float16 f16x8 __attribute__((ext_vector_type(8)));
typedef __attribute__((ext_vector_type(16))) float f32x16;

#define XBB 1160   // per-batch halfs in xsH: 16 rows * 72 + 8 skew (2320 B, 16-aligned)
#define L0C 30
#define NCH 110

__device__ __constant__ int IG0[L0C] = {0,0,0,0,0, 1,1,1,1,1, 2,2,2,2, 3,3,3,3, 4,4,4, 5,5,5, 6,6, 7,7, 8, 9};
__device__ __constant__ int JG0[L0C] = {0,1,2,3,4, 0,1,2,3,4, 1,2,3,4, 1,2,3,4, 2,3,4, 2,3,4, 3,4, 3,4, 4, 4};
// compile-time tables for the unrolled main loop
#define IG0T(c) ((c)<5?0:(c)<10?1:(c)<14?2:(c)<18?3:(c)<21?4:(c)<24?5:(c)<26?6:(c)<28?7:(c)<29?8:9)
#define JG0T(c) ((c)<10?((c)%5):(c)<18?(((c)-10)%4+1):(c)<24?(((c)-18)%3+2):(c)<28?(((c)-24)%2+3):4)

// ---------------- weight repack: coalesced reads, f16 frag stores ----------------
__global__ __launch_bounds__(256)
void CIN_repack(const float* __restrict__ f0, const float* __restrict__ f1,
                uint4* __restrict__ ws)
{
    const int tid  = blockIdx.x * 256 + threadIdx.x;   // 56320 total
    const int n    = tid & 127;
    const int slot = tid >> 7;                          // 0..439
    const int half = slot & 1;
    const int kh   = (slot >> 1) & 1;
    const int ch   = slot >> 2;                         // 0..109
    float v[8];
    if (ch < L0C) {
        const int ig = IG0[ch], jg = JG0[ch];
        const int i = ig * 4 + kh * 2 + half;           // 0..39
#pragma unroll
        for (int t = 0; t < 8; ++t) {
            const int j = jg * 8 + t;                   // 0..39
            float val = 0.f;
            if (i < 39 && j < 39 && j >= i) {
                val = f0[(i * 39 + j) * 128 + n];
                if (j > i) val += f0[(j * 39 + i) * 128 + n];   // symmetric fold
            }
            v[t] = val;
        }
    } else {
        const int c1 = ch - L0C;
        const int jg = c1 / 5, ig = c1 - jg * 5;
        const int j = jg * 4 + kh * 2 + half;           // 0..63
#pragma unroll
        for (int t = 0; t < 8; ++t) {
            const int i = ig * 8 + t;                   // 0..39
            v[t] = (i < 39) ? f1[(i * 64 + j) * 128 + n] : 0.f;
        }
    }
    union { h2 h[4]; uint4 q; } pk;
#pragma unroll
    for (int t = 0; t < 4; ++t)
        pk.h[t] = h2{(_Float16)v[2 * t], (_Float16)v[2 * t + 1]};
    const int lane = half * 32 + (n & 31);
    const int cg   = n >> 5;
    ws[ch * 512 + kh * 256 + cg * 64 + lane] = pk.q;
}

// ---------------- main: grid 1024, 4 batches/block, 4 waves ----------------
__global__ __launch_bounds__(256, 4)
void CIN_main(const float* __restrict__ x,
              const char* __restrict__ wsB,
              const float* __restrict__ dw,
              const float* __restrict__ db,
              float* __restrict__ out)
{
    __shared__ __align__(16) _Float16 xsH[4 * XBB];    // [bb]: 16 rows of 72 (i<=39 used)
    __shared__ __align__(4)  _Float16 hsH[4][64][18];  // [bb][j][d]
    __shared__ float dws[192];
    __shared__ float red[4][4];

    const int tid  = threadIdx.x;
    const int w    = tid >> 6;     // col-quarter: n in [w*32, w*32+32)
    const int lane = tid & 63;
    const int half = lane >> 5;
    const int d    = lane & 15;
    const int bsel = (lane >> 4) & 1;
    const int col  = lane & 31;

    // B frag base; rebase +2048 so kh offsets {-2048,+2048} fit imm13
    const char* wbase = wsB + lane * 16 + w * 1024 + 2048;
    f16x8 Bb[2][2];                // [phase][kh]
    auto loadBg = [&](int ch, f16x8 (&B)[2]) {
        const char* p0 = wbase + (size_t)ch * 8192;
        B[0] = *(const f16x8*)(p0 - 2048);
        B[1] = *(const f16x8*)(p0 + 2048);
    };

    loadBg(0, Bb[0]);              // before x staging: latency hidden
    loadBg(1, Bb[1]);

    // ---- stage x for 4 batches as f16 (624 float4) ----
    const float4* xg4 = (const float4*)(x + (size_t)blockIdx.x * 4 * 624);
    for (int e4 = tid; e4 < 624; e4 += 256) {
        float4 v = xg4[e4];
        int bb = e4 / 156, r = e4 - bb * 156;
        int i = r >> 2, d0 = (r & 3) * 4;
        _Float16* bp = xsH + bb * XBB + i;
        bp[(d0 + 0) * 72] = (_Float16)v.x; bp[(d0 + 1) * 72] = (_Float16)v.y;
        bp[(d0 + 2) * 72] = (_Float16)v.z; bp[(d0 + 3) * 72] = (_Float16)v.w;
    }
    if (tid < 64) { int bb = tid >> 4, dd = tid & 15; xsH[bb * XBB + dd * 72 + 39] = (_Float16)0.f; }
    if (tid < 192) dws[tid] = dw[tid];
    __syncthreads();

    // per-(p) LDS row base for this lane's batch: 16-B aligned (2320 and 144 are x16)
    const _Float16* xrow[2] = {
        xsH + (0 * 2 + bsel) * XBB + d * 72,
        xsH + (1 * 2 + bsel) * XBB + d * 72
    };

    f32x16 acc[2];
#pragma unroll
    for (int p = 0; p < 2; ++p)
#pragma unroll
        for (int r = 0; r < 16; ++r) acc[p][r] = 0.f;

    h2 xiv2[2][2];

    // ---------------- layer 0: 30 folded chunks, fully unrolled ----------------
#pragma unroll
    for (int c = 0; c < L0C; ++c) {
        const int ig = IG0T(c);
        const int jg = JG0T(c);
        if ((c == 0) || (IG0T(c) != IG0T(c - 1))) {
#pragma unroll
            for (int p = 0; p < 2; ++p)
#pragma unroll
                for (int kh = 0; kh < 2; ++kh) {
                    _Float16 s = xrow[p][ig * 4 + kh * 2 + half];
                    xiv2[p][kh] = h2{s, s};
                }
        }
#pragma unroll
        for (int p = 0; p < 2; ++p) {
            union { f16x8 v; h2 h[4]; } xj;
            xj.v = *(const f16x8*)(xrow[p] + jg * 8);          // one ds_read_b128
            union { h2 h[4]; f16x8 v; } a0, a1;
#pragma unroll
            for (int q = 0; q < 4; ++q) {
                a0.h[q] = xiv2[p][0] * xj.h[q];                // v_pk_mul_f16
                a1.h[q] = xiv2[p][1] * xj.h[q];
            }
            acc[p] = __builtin_amdgcn_mfma_f32_32x32x16_f16(a0.v, Bb[c & 1][0], acc[p], 0, 0, 0);
            acc[p] = __builtin_amdgcn_mfma_f32_32x32x16_f16(a1.v, Bb[c & 1][1], acc[p], 0, 0, 0);
        }
        loadBg(c + 2, Bb[c & 1]);   // max c+2 = 31 < 110; fills L1 ch 30/31
    }

    // ---------------- layer-0 epilogue ----------------
    float cs[4] = {0.f, 0.f, 0.f, 0.f};
    if (w < 2) {
        // n = w*32+col < 64 -> h = relu(z0) into LDS (f16)
#pragma unroll
        for (int p = 0; p < 2; ++p)
#pragma unroll
            for (int r = 0; r < 16; r += 2) {
                const int row = (r & 3) + 8 * (r >> 2) + 4 * half;
                h2 pr = h2{(_Float16)fmaxf(acc[p][r],     0.f),
                           (_Float16)fmaxf(acc[p][r + 1], 0.f)};
                *(h2*)&hsH[p * 2 + (row >> 4)][w * 32 + col][row & 15] = pr;
            }
    } else {
        const float dwv = dws[(w - 2) * 32 + col];      // dw[n-64]
#pragma unroll
        for (int p = 0; p < 2; ++p)
#pragma unroll
            for (int r = 0; r < 16; ++r) {
                const int row = (r & 3) + 8 * (r >> 2) + 4 * half;
                cs[p * 2 + (row >> 4)] += fmaxf(acc[p][r], 0.f) * dwv;
            }
    }
#pragma unroll
    for (int p = 0; p < 2; ++p)
#pragma unroll
        for (int r = 0; r < 16; ++r) acc[p][r] = 0.f;
    __syncthreads();   // h visible to all waves

    // ---------------- layer 1: 8 outer x 10 unrolled chunks (30..109) ----------------
    // phase continuity: ch 30 -> parity 0 -> Bb[0] (prefetched at c=28) OK
#pragma unroll 1
    for (int o2 = 0; o2 < 8; ++o2) {
#pragma unroll
        for (int u = 0; u < 10; ++u) {
            const int ch = L0C + o2 * 10 + u;
            const int ig2 = u % 5;
            if (ig2 == 0) {
                const int jb = (o2 * 2 + u / 5) * 4;
#pragma unroll
                for (int p = 0; p < 2; ++p)
#pragma unroll
                    for (int kh = 0; kh < 2; ++kh) {
                        _Float16 s = hsH[p * 2 + bsel][jb + kh * 2 + half][d];
                        xiv2[p][kh] = h2{s, s};
                    }
            }
#pragma unroll
            for (int p = 0; p < 2; ++p) {
                union { f16x8 v; h2 h[4]; } xj;
                xj.v = *(const f16x8*)(xrow[p] + ig2 * 8);     // one ds_read_b128
                union { h2 h[4]; f16x8 v; } a0, a1;
#pragma unroll
                for (int q = 0; q < 4; ++q) {
                    a0.h[q] = xiv2[p][0] * xj.h[q];
                    a1.h[q] = xiv2[p][1] * xj.h[q];
                }
                acc[p] = __builtin_amdgcn_mfma_f32_32x32x16_f16(a0.v, Bb[u & 1][0], acc[p], 0, 0, 0);
                acc[p] = __builtin_amdgcn_mfma_f32_32x32x16_f16(a1.v, Bb[u & 1][1], acc[p], 0, 0, 0);
            }
            int chn = ch + 2; if (chn > NCH - 1) chn = NCH - 1;
            loadBg(chn, Bb[u & 1]);
        }
    }

    // ---------------- layer-1 epilogue + reduction ----------------
    {
        const float dwv = dws[64 + w * 32 + col];
#pragma unroll
        for (int p = 0; p < 2; ++p)
#pragma unroll
            for (int r = 0; r < 16; ++r) {
                const int row = (r & 3) + 8 * (r >> 2) + 4 * half;
                cs[p * 2 + (row >> 4)] += fmaxf(acc[p][r], 0.f) * dwv;
            }
    }
#pragma unroll
    for (int rr = 0; rr < 4; ++rr)
#pragma unroll
        for (int off = 32; off > 0; off >>= 1)
            cs[rr] += __shfl_xor(cs[rr], off, 64);
    if (lane == 0) {
#pragma unroll
        for (int rr = 0; rr < 4; ++rr) red[w][rr] = cs[rr];
    }
    __syncthreads();
    if (tid < 4)
        out[blockIdx.x * 4 + tid] = red[0][tid] + red[1][tid] + red[2][tid] + red[3][tid] + db[0];
}

extern "C" void kernel_launch(void* const* d_in, const int* in_sizes, int n_in,
                              void* d_out, int out_size, void* d_ws, size_t ws_size,
                              hipStream_t stream)
{
    const float* x  = (const float*)d_in[0];
    const float* f0 = (const float*)d_in[1];
    const float* f1 = (const float*)d_in[2];
    const float* dw = (const float*)d_in[3];
    const float* db = (const float*)d_in[4];
    float* out = (float*)d_out;

    CIN_repack<<<dim3(220), dim3(256), 0, stream>>>(f0, f1, (uint4*)d_ws);
    CIN_main<<<dim3(1024), dim3(256), 0, stream>>>(x, (const char*)d_ws, dw, db, out);
}

// Round 11
// 123.874 us; speedup vs baseline: 1.0102x; 1.0081x over previous
//
#include <hip/hip_runtime.h>

// B=4096, F0=39, D=16, L=(128,128), H1=64
// Round-11: r9/r10 structure + amdgpu_waves_per_eu(4,4) to force the 128-VGPR tier.
//  - r9/r10 post-mortem: allocator targeted the 8-waves/SIMD tier (VGPR=64, grid caps
//    residency at 4 waves/SIMD anyway) and demoted the A-window registers to per-chunk
//    LDS reads -> LDS pipe serialized with MFMA + B-stream, wall 1353 cyc/chunk.
//  - Fix: amdgpu_waves_per_eu(4,4) => budget 512/4 = 128 VGPR. A-windows live in regs:
//    xwin[2][20] h2 (40 VGPR) serves BOTH layers (layer-0 j-windows == layer-1 i-windows
//    == x[0..39]). K-loop LDS ops shrink to 4 scalar splat reads per ig/jg group.
//  - mfma_f32_32x32x16_f16; wave = 2 M-tiles (4 batches) x col-quarter (disjoint B).
//  - B: f16 frag-order in d_ws, global->VGPR, copy-free distance-2 prefetch, no K barriers.
//  - Layer 0 symmetric fold: 30 chunks; layer 1: 80 chunks; total 110.
// Layouts (verified):
//  A: lane holds A[m=lane&31][k=(lane>>5)*8+t]
//  B: lane holds B[k=(lane>>5)*8+t][n=lane&31]
//  D: lane holds D[row=(r&3)+8*(r>>2)+4*(lane>>5)][col=lane&31]
// Repacked B layout (BYTES): ch*8192 + kh*4096 + cg*1024 + lane*16  (8 f16/lane)
//  L0 ch=0..29 (IG0/JG0 tables): i=ig*4+kh*2+half, j=jg*8+t; folded upper-tri
//    (W'[i,j]=W[i,j]+W[j,i] for j>i, diag kept, j<i zeroed).
//  L1 ch=30+jg*5+ig (jg<16,ig<5): j=jg*4+kh*2+half, i=ig*8+t, zero-pad i>=39.
// Total: 110 chunks * 8192 B = 901,120 B of d_ws.

typedef _Float16 h2    __attribute__((ext_vector_type(2)));
typedef _Float16 f16x8 __attribute__((ext_vector_type(8)));
typedef __attribute__((ext_vector_type(16))) float f32x16;

#define XBB 1160   // per-batch halfs in xsH: 16 rows * 72 + 8 skew (2320 B, 16-aligned)
#define L0C 30
#define NCH 110

__device__ __constant__ int IG0[L0C] = {0,0,0,0,0, 1,1,1,1,1, 2,2,2,2, 3,3,3,3, 4,4,4, 5,5,5, 6,6, 7,7, 8, 9};
__device__ __constant__ int JG0[L0C] = {0,1,2,3,4, 0,1,2,3,4, 1,2,3,4, 1,2,3,4, 2,3,4, 2,3,4, 3,4, 3,4, 4, 4};
// compile-time tables for the unrolled main loop
#define IG0T(c) ((c)<5?0:(c)<10?1:(c)<14?2:(c)<18?3:(c)<21?4:(c)<24?5:(c)<26?6:(c)<28?7:(c)<29?8:9)
#define JG0T(c) ((c)<10?((c)%5):(c)<18?(((c)-10)%4+1):(c)<24?(((c)-18)%3+2):(c)<28?(((c)-24)%2+3):4)

// ---------------- weight repack: coalesced reads, f16 frag stores ----------------
__global__ __launch_bounds__(256)
void CIN_repack(const float* __restrict__ f0, const float* __restrict__ f1,
                uint4* __restrict__ ws)
{
    const int tid  = blockIdx.x * 256 + threadIdx.x;   // 56320 total
    const int n    = tid & 127;
    const int slot = tid >> 7;                          // 0..439
    const int half = slot & 1;
    const int kh   = (slot >> 1) & 1;
    const int ch   = slot >> 2;                         // 0..109
    float v[8];
    if (ch < L0C) {
        const int ig = IG0[ch], jg = JG0[ch];
        const int i = ig * 4 + kh * 2 + half;           // 0..39
#pragma unroll
        for (int t = 0; t < 8; ++t) {
            const int j = jg * 8 + t;                   // 0..39
            float val = 0.f;
            if (i < 39 && j < 39 && j >= i) {
                val = f0[(i * 39 + j) * 128 + n];
                if (j > i) val += f0[(j * 39 + i) * 128 + n];   // symmetric fold
            }
            v[t] = val;
        }
    } else {
        const int c1 = ch - L0C;
        const int jg = c1 / 5, ig = c1 - jg * 5;
        const int j = jg * 4 + kh * 2 + half;           // 0..63
#pragma unroll
        for (int t = 0; t < 8; ++t) {
            const int i = ig * 8 + t;                   // 0..39
            v[t] = (i < 39) ? f1[(i * 64 + j) * 128 + n] : 0.f;
        }
    }
    union { h2 h[4]; uint4 q; } pk;
#pragma unroll
    for (int t = 0; t < 4; ++t)
        pk.h[t] = h2{(_Float16)v[2 * t], (_Float16)v[2 * t + 1]};
    const int lane = half * 32 + (n & 31);
    const int cg   = n >> 5;
    ws[ch * 512 + kh * 256 + cg * 64 + lane] = pk.q;
}

// ---------------- main: grid 1024, 4 batches/block, 4 waves, FORCED 128-VGPR tier ----
__global__ __launch_bounds__(256)
__attribute__((amdgpu_waves_per_eu(4, 4)))
void CIN_main(const float* __restrict__ x,
              const char* __restrict__ wsB,
              const float* __restrict__ dw,
              const float* __restrict__ db,
              float* __restrict__ out)
{
    __shared__ __align__(16) _Float16 xsH[4 * XBB];    // [bb]: 16 rows of 72 (i<=39 used)
    __shared__ __align__(4)  _Float16 hsH[4][64][18];  // [bb][j][d]
    __shared__ float dws[192];
    __shared__ float red[4][4];

    const int tid  = threadIdx.x;
    const int w    = tid >> 6;     // col-quarter: n in [w*32, w*32+32)
    const int lane = tid & 63;
    const int half = lane >> 5;
    const int d    = lane & 15;
    const int bsel = (lane >> 4) & 1;
    const int col  = lane & 31;

    // B frag base; rebase +2048 so kh offsets {-2048,+2048} fit imm13
    const char* wbase = wsB + lane * 16 + w * 1024 + 2048;
    f16x8 Bb[2][2];                // [phase][kh]
    auto loadBg = [&](int ch, f16x8 (&B)[2]) {
        const char* p0 = wbase + (size_t)ch * 8192;
        B[0] = *(const f16x8*)(p0 - 2048);
        B[1] = *(const f16x8*)(p0 + 2048);
    };

    loadBg(0, Bb[0]);              // before x staging: latency hidden
    loadBg(1, Bb[1]);

    // ---- stage x for 4 batches as f16 (624 float4) ----
    const float4* xg4 = (const float4*)(x + (size_t)blockIdx.x * 4 * 624);
    for (int e4 = tid; e4 < 624; e4 += 256) {
        float4 v = xg4[e4];
        int bb = e4 / 156, r = e4 - bb * 156;
        int i = r >> 2, d0 = (r & 3) * 4;
        _Float16* bp = xsH + bb * XBB + i;
        bp[(d0 + 0) * 72] = (_Float16)v.x; bp[(d0 + 1) * 72] = (_Float16)v.y;
        bp[(d0 + 2) * 72] = (_Float16)v.z; bp[(d0 + 3) * 72] = (_Float16)v.w;
    }
    if (tid < 64) { int bb = tid >> 4, dd = tid & 15; xsH[bb * XBB + dd * 72 + 39] = (_Float16)0.f; }
    if (tid < 192) dws[tid] = dw[tid];
    __syncthreads();

    // per-(p) LDS row base for this lane's batch: 16-B aligned (2320 and 144 are x16)
    const _Float16* xrow[2] = {
        xsH + (0 * 2 + bsel) * XBB + d * 72,
        xsH + (1 * 2 + bsel) * XBB + d * 72
    };

    // ---- xwin: the 5 8-half windows of x[0..39], REGISTERS, serve both layers ----
    h2 xwin[2][20];
#pragma unroll
    for (int p = 0; p < 2; ++p)
#pragma unroll
        for (int w5 = 0; w5 < 5; ++w5) {
            union { f16x8 v; h2 h[4]; } u;
            u.v = *(const f16x8*)(xrow[p] + w5 * 8);    // one ds_read_b128
#pragma unroll
            for (int q = 0; q < 4; ++q) xwin[p][w5 * 4 + q] = u.h[q];
        }

    f32x16 acc[2];
#pragma unroll
    for (int p = 0; p < 2; ++p)
#pragma unroll
        for (int r = 0; r < 16; ++r) acc[p][r] = 0.f;

    h2 xiv2[2][2];

    // ---------------- layer 0: 30 folded chunks, fully unrolled ----------------
#pragma unroll
    for (int c = 0; c < L0C; ++c) {
        const int ig = IG0T(c);
        const int jg = JG0T(c);
        if ((c == 0) || (IG0T(c) != IG0T(c - 1))) {
#pragma unroll
            for (int p = 0; p < 2; ++p)
#pragma unroll
                for (int kh = 0; kh < 2; ++kh) {
                    _Float16 s = xrow[p][ig * 4 + kh * 2 + half];
                    xiv2[p][kh] = h2{s, s};
                }
        }
#pragma unroll
        for (int p = 0; p < 2; ++p) {
            union { h2 h[4]; f16x8 v; } a0, a1;
#pragma unroll
            for (int q = 0; q < 4; ++q) {
                a0.h[q] = xiv2[p][0] * xwin[p][jg * 4 + q];   // v_pk_mul_f16
                a1.h[q] = xiv2[p][1] * xwin[p][jg * 4 + q];
            }
            acc[p] = __builtin_amdgcn_mfma_f32_32x32x16_f16(a0.v, Bb[c & 1][0], acc[p], 0, 0, 0);
            acc[p] = __builtin_amdgcn_mfma_f32_32x32x16_f16(a1.v, Bb[c & 1][1], acc[p], 0, 0, 0);
        }
        loadBg(c + 2, Bb[c & 1]);   // max c+2 = 31 < 110; fills L1 ch 30/31
    }

    // ---------------- layer-0 epilogue ----------------
    float cs[4] = {0.f, 0.f, 0.f, 0.f};
    if (w < 2) {
        // n = w*32+col < 64 -> h = relu(z0) into LDS (f16)
#pragma unroll
        for (int p = 0; p < 2; ++p)
#pragma unroll
            for (int r = 0; r < 16; r += 2) {
                const int row = (r & 3) + 8 * (r >> 2) + 4 * half;
                h2 pr = h2{(_Float16)fmaxf(acc[p][r],     0.f),
                           (_Float16)fmaxf(acc[p][r + 1], 0.f)};
                *(h2*)&hsH[p * 2 + (row >> 4)][w * 32 + col][row & 15] = pr;
            }
    } else {
        const float dwv = dws[(w - 2) * 32 + col];      // dw[n-64]
#pragma unroll
        for (int p = 0; p < 2; ++p)
#pragma unroll
            for (int r = 0; r < 16; ++r) {
                const int row = (r & 3) + 8 * (r >> 2) + 4 * half;
                cs[p * 2 + (row >> 4)] += fmaxf(acc[p][r], 0.f) * dwv;
            }
    }
#pragma unroll
    for (int p = 0; p < 2; ++p)
#pragma unroll
        for (int r = 0; r < 16; ++r) acc[p][r] = 0.f;
    __syncthreads();   // h visible to all waves

    // ---------------- layer 1: 8 outer x 10 unrolled chunks (30..109) ----------------
    // phase continuity: ch 30 -> parity 0 -> Bb[0] (prefetched at c=28) OK
#pragma unroll 1
    for (int o2 = 0; o2 < 8; ++o2) {
#pragma unroll
        for (int u = 0; u < 10; ++u) {
            const int ch = L0C + o2 * 10 + u;
            const int ig2 = u % 5;
            if (ig2 == 0) {
                const int jb = (o2 * 2 + u / 5) * 4;
#pragma unroll
                for (int p = 0; p < 2; ++p)
#pragma unroll
                    for (int kh = 0; kh < 2; ++kh) {
                        _Float16 s = hsH[p * 2 + bsel][jb + kh * 2 + half][d];
                        xiv2[p][kh] = h2{s, s};
                    }
            }
#pragma unroll
            for (int p = 0; p < 2; ++p) {
                union { h2 h[4]; f16x8 v; } a0, a1;
#pragma unroll
                for (int q = 0; q < 4; ++q) {
                    a0.h[q] = xiv2[p][0] * xwin[p][ig2 * 4 + q];
                    a1.h[q] = xiv2[p][1] * xwin[p][ig2 * 4 + q];
                }
                acc[p] = __builtin_amdgcn_mfma_f32_32x32x16_f16(a0.v, Bb[u & 1][0], acc[p], 0, 0, 0);
                acc[p] = __builtin_amdgcn_mfma_f32_32x32x16_f16(a1.v, Bb[u & 1][1], acc[p], 0, 0, 0);
            }
            int chn = ch + 2; if (chn > NCH - 1) chn = NCH - 1;
            loadBg(chn, Bb[u & 1]);
        }
    }

    // ---------------- layer-1 epilogue + reduction ----------------
    {
        const float dwv = dws[64 + w * 32 + col];
#pragma unroll
        for (int p = 0; p < 2; ++p)
#pragma unroll
            for (int r = 0; r < 16; ++r) {
                const int row = (r & 3) + 8 * (r >> 2) + 4 * half;
                cs[p * 2 + (row >> 4)] += fmaxf(acc[p][r], 0.f) * dwv;
            }
    }
#pragma unroll
    for (int rr = 0; rr < 4; ++rr)
#pragma unroll
        for (int off = 32; off > 0; off >>= 1)
            cs[rr] += __shfl_xor(cs[rr], off, 64);
    if (lane == 0) {
#pragma unroll
        for (int rr = 0; rr < 4; ++rr) red[w][rr] = cs[rr];
    }
    __syncthreads();
    if (tid < 4)
        out[blockIdx.x * 4 + tid] = red[0][tid] + red[1][tid] + red[2][tid] + red[3][tid] + db[0];
}

extern "C" void kernel_launch(void* const* d_in, const int* in_sizes, int n_in,
                              void* d_out, int out_size, void* d_ws, size_t ws_size,
                              hipStream_t stream)
{
    const float* x  = (const float*)d_in[0];
    const float* f0 = (const float*)d_in[1];
    const float* f1 = (const float*)d_in[2];
    const float* dw = (const float*)d_in[3];
    const float* db = (const float*)d_in[4];
    float* out = (float*)d_out;

    CIN_repack<<<dim3(220), dim3(256), 0, stream>>>(f0, f1, (uint4*)d_ws);
    CIN_main<<<dim3(1024), dim3(256), 0, stream>>>(x, (const char*)d_ws, dw, db, out);
}